// Round 5
// baseline (1016.562 us; speedup 1.0000x reference)
//
#include <hip/hip_runtime.h>
#include <hip/hip_bf16.h>

typedef __bf16 bf16;
typedef bf16 bf16x8 __attribute__((ext_vector_type(8)));
typedef float f32x4 __attribute__((ext_vector_type(4)));

struct alignas(8) bh4 { bf16 v[4]; };

// async global->LDS, 16B per lane. LDS dest must be wave-uniform base + lane*16.
__device__ __forceinline__ void glds16(const bf16* g, bf16* l) {
  __builtin_amdgcn_global_load_lds(
      (const __attribute__((address_space(1))) void*)g,
      (__attribute__((address_space(3))) void*)l, 16, 0, 0);
}

// log2(e) / sqrt(128): folded into Q so softmax uses exp2 (native v_exp_f32)
#define QSCALE (1.4426950408889634f / 11.313708498984761f)

// fp32 -> bf16, two segments in one launch (x and w_qkv).
__global__ void convert2_to_bf16(const float* __restrict__ s0, bf16* __restrict__ d0, long n0,
                                 const float* __restrict__ s1, bf16* __restrict__ d1, long n1) {
  const long total = (n0 + n1) >> 3;
  const long stride = (long)gridDim.x * blockDim.x;
  for (long g = (long)blockIdx.x * blockDim.x + threadIdx.x; g < total; g += stride) {
    long i = g << 3;
    const float* s; bf16* d;
    if (i < n0) { s = s0 + i; d = d0 + i; }
    else        { s = s1 + (i - n0); d = d1 + (i - n0); }
    float4 a = *(const float4*)s;
    float4 b = *(const float4*)(s + 4);
    bf16x8 o;
    o[0] = (bf16)a.x; o[1] = (bf16)a.y; o[2] = (bf16)a.z; o[3] = (bf16)a.w;
    o[4] = (bf16)b.x; o[5] = (bf16)b.y; o[6] = (bf16)b.z; o[7] = (bf16)b.w;
    *(bf16x8*)d = o;
  }
}

__global__ void convert_to_bf16(const float* __restrict__ s, bf16* __restrict__ dst,
                                long n) {
  const long stride = (long)gridDim.x * blockDim.x * 8;
  for (long i = ((long)blockIdx.x * blockDim.x + threadIdx.x) * 8; i < n; i += stride) {
    float4 a = *(const float4*)(s + i);
    float4 b = *(const float4*)(s + i + 4);
    bf16x8 o;
    o[0] = (bf16)a.x; o[1] = (bf16)a.y; o[2] = (bf16)a.z; o[3] = (bf16)a.w;
    o[4] = (bf16)b.x; o[5] = (bf16)b.y; o[6] = (bf16)b.z; o[7] = (bf16)b.w;
    *(bf16x8*)(dst + i) = o;
  }
}

// ---------------- GEMM: C = A (M,K) * Bw^T, Bw is (N,K) row-major ----------
// 128x128 tile, BK=32, 4 waves 2x2 (verified rounds 3-4).
template <int MODE>
__global__ void gemm_bt(const bf16* __restrict__ A, const bf16* __restrict__ Bw,
                        void* __restrict__ C0v, bf16* __restrict__ C1,
                        bf16* __restrict__ C2, int M, int N, int K) {
  __shared__ __align__(16) bf16 sA[128 * 32];
  __shared__ __align__(16) bf16 sB[128 * 32];
  const int tid = threadIdx.x;
  const int lane = tid & 63, wid = tid >> 6;
  const int wm = wid & 1, wn = wid >> 1;
  const int quad = lane >> 4, l16 = lane & 15;
  const int bm = blockIdx.y * 128, bn = blockIdx.x * 128;

  f32x4 acc[4][4] = {};

  const int srow = tid >> 2, scol = (tid & 3) << 3;
  const bf16* gA = A + (size_t)(bm + srow) * K + scol;
  const bf16* gB = Bw + (size_t)(bn + srow) * K + scol;
  const size_t row64 = (size_t)64 * K;

  for (int k0 = 0; k0 < K; k0 += 32) {
    glds16(gA + k0, &sA[tid * 8]);
    glds16(gA + k0 + row64, &sA[2048 + tid * 8]);
    glds16(gB + k0, &sB[tid * 8]);
    glds16(gB + k0 + row64, &sB[2048 + tid * 8]);
    __syncthreads();
    bf16x8 af[4], bff[4];
#pragma unroll
    for (int mt = 0; mt < 4; ++mt)
      af[mt] = *(const bf16x8*)&sA[(wm * 64 + mt * 16 + l16) * 32 + quad * 8];
#pragma unroll
    for (int nt = 0; nt < 4; ++nt)
      bff[nt] = *(const bf16x8*)&sB[(wn * 64 + nt * 16 + l16) * 32 + quad * 8];
#pragma unroll
    for (int mt = 0; mt < 4; ++mt)
#pragma unroll
      for (int nt = 0; nt < 4; ++nt)
        acc[mt][nt] = __builtin_amdgcn_mfma_f32_16x16x32_bf16(af[mt], bff[nt], acc[mt][nt], 0, 0, 0);
    __syncthreads();
  }

  if (MODE == 0) {
    bf16* C0 = (bf16*)C0v;
    const int which = blockIdx.x >> 4;
    const int h = blockIdx.x & 15;
#pragma unroll
    for (int mt = 0; mt < 4; ++mt) {
      const int m0 = bm + wm * 64 + mt * 16 + quad * 4;
      const int b = m0 >> 11, t0 = m0 & 2047;
#pragma unroll
      for (int nt = 0; nt < 4; ++nt) {
        const int hd = wn * 64 + nt * 16 + l16;
        if (which == 0) {
          bf16* dst = C0 + (((size_t)(b * 16 + h) * 2048 + t0) * 128 + hd);
#pragma unroll
          for (int r = 0; r < 4; ++r) dst[(size_t)r * 128] = (bf16)(acc[mt][nt][r] * QSCALE);
        } else if (which == 1) {
          bf16* dst = C1 + (((size_t)(b * 16 + h) * 2048 + t0) * 128 + hd);
#pragma unroll
          for (int r = 0; r < 4; ++r) dst[(size_t)r * 128] = (bf16)acc[mt][nt][r];
        } else {
          bh4 pk;
#pragma unroll
          for (int r = 0; r < 4; ++r) pk.v[r] = (bf16)acc[mt][nt][r];
          *(bh4*)(C2 + ((size_t)((b * 16 + h) * 128 + hd) * 2048 + t0)) = pk;
        }
      }
    }
  } else {
    float* C0 = (float*)C0v;  // fp32 final output
#pragma unroll
    for (int mt = 0; mt < 4; ++mt) {
      const int m0 = bm + wm * 64 + mt * 16 + quad * 4;
#pragma unroll
      for (int nt = 0; nt < 4; ++nt) {
        const int n = bn + wn * 64 + nt * 16 + l16;
#pragma unroll
        for (int r = 0; r < 4; ++r)
          C0[(size_t)(m0 + r) * N + n] = acc[mt][nt][r];
      }
    }
  }
}

// ---------------- Flash attention, transposed-S formulation ----------------
// S^T = K·Q^T (softmax on quad/reg axes), O^T = V^T·P^T, Q in registers.
// LDS: sK (16 KB) + sV (16 KB); P lives in the sK region after S^T (extra
// barrier). Epilogue transpose region 34 KB is the LDS max -> 4 blocks/CU.
__global__ __launch_bounds__(256, 4)
void attn_kernel(const bf16* __restrict__ Q, const bf16* __restrict__ Kb,
                 const bf16* __restrict__ Vt, const int* __restrict__ mask,
                 bf16* __restrict__ Y) {
  __shared__ __align__(16) bf16 smem[17408];  // 34816 B
  bf16* sK = smem;                 // loop: 64 keys x 128 hd (swizzled), 16 KB
  bf16* sV = smem + 8192;          // loop: 128 hd x 64 keys (swizzled), 16 KB

  const int tid = threadIdx.x;
  const int lane = tid & 63, w = tid >> 6;
  const int quad = lane >> 4, l16 = lane & 15;
  const int bh = blockIdx.x, b = bh >> 4, h = bh & 15;
  const int qt = blockIdx.y;
  const size_t head = (size_t)bh * (2048 * 128);

  // Q fragments resident: B-operand layout (lane = query, k = quad*8+j)
  bf16x8 qf[2][4];
#pragma unroll
  for (int nt = 0; nt < 2; ++nt) {
    const int t = qt * 128 + w * 32 + nt * 16 + l16;
    const bf16* g = Q + head + (size_t)t * 128 + quad * 8;
#pragma unroll
    for (int kk = 0; kk < 4; ++kk)
      qf[nt][kk] = *(const bf16x8*)(g + kk * 32);
  }

  f32x4 o[8][2] = {};                       // O^T: rows hd (8 tiles), cols query
  float mrow[2] = {-3.0e38f, -3.0e38f};
  float lrow[2] = {0.0f, 0.0f};

  const int* maskb = mask + b * 2048;
  // per-wave P region inside sK: 32 q x 64 k, stride 64, 16B-unit xor swizzle
  bf16* sPw = sK + w * 2048;

  for (int kt = 0; kt < 32; ++kt) {
    const int key0 = kt * 64;
    {  // stage K tile (64 keys x 128 hd = 16 chunks/row), swizzled
      const int cp = lane & 15;
      const int rbase = w * 16 + (lane >> 4);
#pragma unroll
      for (int p = 0; p < 4; ++p) {
        const int row = rbase + p * 4;
        const int c = (cp & 8) | ((cp ^ row) & 7);
        glds16(Kb + head + (size_t)(key0 + row) * 128 + c * 8,
               &sK[(w * 16 + p * 4) * 128 + lane * 8]);
      }
    }
    {  // stage V^T tile (128 hd x 64 keys = 8 chunks/row), swizzled
      const int cp = lane & 7;
      const int rbase = w * 32 + (lane >> 3);
#pragma unroll
      for (int p = 0; p < 4; ++p) {
        const int row = rbase + p * 8;
        const int c = cp ^ (row & 7);
        glds16(Vt + head + (size_t)row * 2048 + key0 + c * 8,
               &sV[(w * 32 + p * 8) * 64 + lane * 8]);
      }
    }
    __syncthreads();  // B1: staging DMA drained

    // S^T = K · Q^T : st[mt=key-tile][nt=query-tile]
    f32x4 st[4][2] = {};
#pragma unroll
    for (int kk = 0; kk < 4; ++kk) {
      bf16x8 ak[4];
#pragma unroll
      for (int mt = 0; mt < 4; ++mt) {
        const int row = mt * 16 + l16;
        const int c = kk * 4 + quad;
        const int cp = (c & 8) | ((c ^ row) & 7);
        ak[mt] = *(const bf16x8*)&sK[row * 128 + cp * 8];
      }
#pragma unroll
      for (int mt = 0; mt < 4; ++mt)
#pragma unroll
        for (int nt = 0; nt < 2; ++nt)
          st[mt][nt] = __builtin_amdgcn_mfma_f32_16x16x32_bf16(ak[mt], qf[nt][kk], st[mt][nt], 0, 0, 0);
    }
    __syncthreads();  // B2: all waves done reading sK -> P may overwrite it

    // additive mask bias for this wave's keys: key = 16*mt + 4*quad + r
    const int4* mp = (const int4*)(maskb + key0);
    float bias[4][4];
#pragma unroll
    for (int mt = 0; mt < 4; ++mt) {
      const int4 mmv = mp[mt * 4 + quad];
      const int* mi = (const int*)&mmv;
#pragma unroll
      for (int r = 0; r < 4; ++r) bias[mt][r] = (mi[r] != 0) ? 0.0f : -1.0e30f;
    }

    // online softmax per query column (2/lane); reductions = 2 shuffles
    float alph[2];
#pragma unroll
    for (int nt = 0; nt < 2; ++nt) {
      float mx = -1.0e30f;
#pragma unroll
      for (int mt = 0; mt < 4; ++mt)
#pragma unroll
        for (int r = 0; r < 4; ++r) {
          const float v = st[mt][nt][r] + bias[mt][r];
          st[mt][nt][r] = v;
          mx = fmaxf(mx, v);
        }
      mx = fmaxf(mx, __shfl_xor(mx, 16));
      mx = fmaxf(mx, __shfl_xor(mx, 32));
      const float newm = fmaxf(mrow[nt], mx);
      alph[nt] = exp2f(mrow[nt] - newm);
      mrow[nt] = newm;
      float rs = 0.0f;
      const int q = nt * 16 + l16;
      bf16* pw = sPw + q * 64;
      const int sw = q & 7;
#pragma unroll
      for (int mt = 0; mt < 4; ++mt) {
        bh4 pk;
#pragma unroll
        for (int r = 0; r < 4; ++r) {
          const float p = exp2f(st[mt][nt][r] - newm);  // masked -> underflow 0
          rs += p;
          pk.v[r] = (bf16)p;
        }
        // 16B unit u = mt*2 + (quad>>1), half = quad&1, swizzle u^=q&7
        *(bh4*)&pw[(((mt * 2 + (quad >> 1)) ^ sw) << 3) + ((quad & 1) << 2)] = pk;
      }
      rs += __shfl_xor(rs, 16);
      rs += __shfl_xor(rs, 32);
      lrow[nt] = lrow[nt] * alph[nt] + rs;
    }
    if (__any(alph[0] != 1.0f || alph[1] != 1.0f)) {
#pragma unroll
      for (int mt = 0; mt < 8; ++mt)
#pragma unroll
        for (int nt = 0; nt < 2; ++nt)
#pragma unroll
          for (int r = 0; r < 4; ++r)
            o[mt][nt][r] *= alph[nt];
    }

    // O^T += V^T · P^T  (sPw wave-local: same-wave ds ordering suffices)
#pragma unroll
    for (int kk = 0; kk < 2; ++kk) {
      bf16x8 bp[2];
#pragma unroll
      for (int nt = 0; nt < 2; ++nt) {
        const int q = nt * 16 + l16;
        const int u = kk * 4 + quad;
        bp[nt] = *(const bf16x8*)&sPw[q * 64 + ((u ^ (q & 7)) << 3)];
      }
#pragma unroll
      for (int mt = 0; mt < 8; ++mt) {
        const int row = mt * 16 + l16;
        const int c = kk * 4 + quad;
        bf16x8 av = *(const bf16x8*)&sV[row * 64 + (c ^ (row & 7)) * 8];
#pragma unroll
        for (int nt = 0; nt < 2; ++nt)
          o[mt][nt] = __builtin_amdgcn_mfma_f32_16x16x32_bf16(av, bp[nt], o[mt][nt], 0, 0, 0);
      }
    }
    __syncthreads();  // B3: sV + P reads done before next staging
  }

  // epilogue: normalize, transpose O^T->O via per-wave LDS region, 16B stores
  bf16* sOw = smem + w * 4352;  // 32 rows x 136 stride
#pragma unroll
  for (int nt = 0; nt < 2; ++nt) {
    const float inv = 1.0f / lrow[nt];
#pragma unroll
    for (int mt = 0; mt < 8; ++mt) {
      bh4 pk;
#pragma unroll
      for (int r = 0; r < 4; ++r) pk.v[r] = (bf16)(o[mt][nt][r] * inv);
      *(bh4*)&sOw[(nt * 16 + l16) * 136 + mt * 16 + quad * 4] = pk;
    }
  }
  // same-wave write->read: lgkmcnt ordering suffices, no barrier
  {
    const int col = (lane & 15) * 8;
#pragma unroll
    for (int p = 0; p < 8; ++p) {
      const int row = p * 4 + (lane >> 4);
      int4 v = *(const int4*)&sOw[row * 136 + col];
      const int token = qt * 128 + w * 32 + row;
      *(int4*)(Y + ((size_t)(b * 2048 + token)) * 2048 + h * 128 + col) = v;
    }
  }
}

extern "C" void kernel_launch(void* const* d_in, const int* in_sizes, int n_in,
                              void* d_out, int out_size, void* d_ws, size_t ws_size,
                              hipStream_t stream) {
  const float* x_raw  = (const float*)d_in[0];
  const int*   mask   = (const int*)d_in[1];
  const float* wq_raw = (const float*)d_in[2];
  const float* wo_raw = (const float*)d_in[3];
  float* out = (float*)d_out;  // reference output dtype is fp32

  char* ws = (char*)d_ws;
  const size_t MB = 1024 * 1024;
  bf16* xb  = (bf16*)(ws + 256);              // 32 MiB  (x bf16; later reused as yb)
  bf16* wqb = (bf16*)(ws + 256 + 32 * MB);    // 24 MiB  (w_qkv bf16; later reused as wob)
  bf16* qb  = (bf16*)(ws + 256 + 56 * MB);    // 32 MiB  (B,H,T,HD) pre-scaled
  bf16* kb  = (bf16*)(ws + 256 + 88 * MB);    // 32 MiB  (B,H,T,HD)
  bf16* vt  = (bf16*)(ws + 256 + 120 * MB);   // 32 MiB  (B,H,HD,T)
  bf16* yb  = xb;                             // attention output (B,T,D)
  bf16* wob = wqb;                            // w_o bf16 (converted after gemm1)

  convert2_to_bf16<<<1024, 256, 0, stream>>>(x_raw, xb, (long)in_sizes[0],
                                             wq_raw, wqb, (long)in_sizes[2]);

  // qkv projection (M=8192, N=6144, K=2048), scatter to per-head layouts
  gemm_bt<0><<<dim3(48, 64), 256, 0, stream>>>(xb, wqb, qb, kb, vt, 8192, 6144, 2048);

  // w_o conversion (overwrites wqb region — dead after gemm1)
  convert_to_bf16<<<1024, 256, 0, stream>>>(wo_raw, wob, (long)in_sizes[3]);

  // fused flash attention (writes yb = xb region — x dead after gemm1)
  attn_kernel<<<dim3(64, 16), 256, 0, stream>>>(qb, kb, vt, mask, yb);

  // output projection (M=8192, N=2048, K=2048), fp32 out
  gemm_bt<1><<<dim3(16, 64), 256, 0, stream>>>(yb, wob, out, nullptr, nullptr, 8192, 2048, 2048);
}